// Round 3
// baseline (792.167 us; speedup 1.0000x reference)
//
#include <hip/hip_runtime.h>

#define D 64
#define ACH 6250   // edges per slice-scatter block
#define LSLOT 3584 // per-slice edge-log capacity

typedef __attribute__((ext_vector_type(8))) short short8;   // 8 bf16 (4 VGPRs)
typedef __attribute__((ext_vector_type(4))) float f32x4;

__device__ __forceinline__ unsigned short f2bf(float f) {
    unsigned u = __float_as_uint(f);
    u = (u + 0x7fff + ((u >> 16) & 1)) >> 16;   // RNE
    return (unsigned short)u;
}
__device__ __forceinline__ float bf_lo(unsigned u) { return __uint_as_float(u << 16); }
__device__ __forceinline__ float bf_hi(unsigned u) { return __uint_as_float(u & 0xffff0000u); }

// R14: slice-scatter — each block bins its 6250-edge chunk by 64-node slice in
// LDS (LDS atomics + prefix-sum), reserves per-slice global ranges with ONE
// atomic per (block,slice) (~100k total vs 800k per-edge), appends slice-sorted
// packed (dst16|src16) edges to a per-slice edge log.
// Block roles in one launch (independent work, co-resident):
//  [0, nsb)            : slice-scatter
//  [nsb, nsb+ncb)      : convert  — x fp32 -> xb bf16 (pad rows zeroed)
//  [nsb+ncb, +64)      : prep     — 4 weight mats -> bf16 transposed
__global__ __launch_bounds__(256) void prep_scatter_kernel(
    const int* __restrict__ src, const int* __restrict__ dst,
    unsigned* __restrict__ gcur, unsigned* __restrict__ elog,
    int n_edges, int S, int nsb,
    const float* __restrict__ x, unsigned short* __restrict__ xb,
    int n4, int n4p, int ncb,
    const float* __restrict__ w1_0, const float* __restrict__ w2_0,
    const float* __restrict__ w1_1, const float* __restrict__ w2_1,
    unsigned short* __restrict__ wt)
{
    __shared__ int cnt[784], start[784], cur[784], gb[784];
    __shared__ int wsum[4];
    __shared__ unsigned reorder[6272];

    const int b   = blockIdx.x;
    const int tid = threadIdx.x;

    if (b < nsb) {
        const int e0 = b * ACH;
        const int nE = (n_edges - e0 < ACH) ? (n_edges - e0) : ACH;

        for (int j = tid; j < 784; j += 256) cnt[j] = 0;
        __syncthreads();

        for (int i = tid; i < nE; i += 256)
            atomicAdd(&cnt[dst[e0 + i] >> 6], 1);
        __syncthreads();

        {   // exclusive prefix over cnt[0..784)
            int t4 = tid * 4;
            int c0 = 0, c1 = 0, c2 = 0, c3 = 0;
            if (t4 < 784) { c0 = cnt[t4]; c1 = cnt[t4+1]; c2 = cnt[t4+2]; c3 = cnt[t4+3]; }
            int lsum = c0 + c1 + c2 + c3;
            int lane = tid & 63, wv = tid >> 6;
            int xs = lsum;
            #pragma unroll
            for (int o = 1; o < 64; o <<= 1) {
                int y = __shfl_up(xs, o, 64);
                if (lane >= o) xs += y;
            }
            if (lane == 63) wsum[wv] = xs;
            __syncthreads();
            int wo = 0;
            for (int w = 0; w < wv; ++w) wo += wsum[w];
            int excl = wo + xs - lsum;
            if (t4 < 784) {
                start[t4]   = excl;                cur[t4]   = excl;
                start[t4+1] = excl + c0;           cur[t4+1] = excl + c0;
                start[t4+2] = excl + c0 + c1;      cur[t4+2] = excl + c0 + c1;
                start[t4+3] = excl + c0 + c1 + c2; cur[t4+3] = excl + c0 + c1 + c2;
            }
        }
        __syncthreads();

        for (int j = tid; j < S; j += 256) {
            int c = cnt[j];
            gb[j] = c ? (int)atomicAdd(&gcur[j], (unsigned)c) : 0;
        }

        for (int i = tid; i < nE; i += 256) {
            int d = dst[e0 + i];
            int s = src[e0 + i];
            int r = atomicAdd(&cur[d >> 6], 1);
            reorder[r] = ((unsigned)d << 16) | (unsigned)s;
        }
        __syncthreads();

        for (int i = tid; i < nE; i += 256) {
            unsigned v = reorder[i];
            int sl  = v >> 22;                 // dst >> 6
            int idx = gb[sl] + (i - start[sl]);
            if (idx < LSLOT) elog[(size_t)sl * LSLOT + idx] = v;
        }
    } else if (b < nsb + ncb) {
        int i = (b - nsb) * 256 + tid;
        if (i < n4) {
            f32x4 v = __builtin_nontemporal_load((const f32x4*)(x + (size_t)i * 4));
            ushort4 o;
            o.x = f2bf(v.x); o.y = f2bf(v.y); o.z = f2bf(v.z); o.w = f2bf(v.w);
            *(ushort4*)(xb + (size_t)i * 4) = o;
        } else if (i < n4p) {
            *(ushort4*)(xb + (size_t)i * 4) = make_ushort4(0, 0, 0, 0);  // pad rows
        }
    } else {
        int i = (b - nsb - ncb) * 256 + tid;   // 0..16383
        int m = i >> 12, r = i & 4095;
        int n = r >> 6, k = r & 63;
        const float* w = (m == 0) ? w1_0 : (m == 1) ? w2_0 : (m == 2) ? w1_1 : w2_1;
        wt[i] = f2bf(w[k * 64 + n]);
    }
}

// R15: fused gather+dense, one block per 64-node slice.
//  P0: stage weights (bf16 LDS) + self rows into f32 LDS accumulator.
//  P1: stream the slice's edge log; 16 lanes/edge, 4 edges/wave-iter; LDS
//      f32 atomicAdd into acc (per-CU atomics, no global traffic, exact-degree
//      reads vs old gather's unconditional 24 rows).
//  P2: build bf16 A-fragments from acc, then the verified W1/tanh/W2 MFMA
//      pipeline (C/D: col=lane&15, row=quad*4+reg; wave-private tanh LDS
//      round-trip, no barrier between matmuls).
// acc padded to [64][68] f32: fragment reads land 2-way (free); ds_add worst
// ~8-way on a few instrs (watch SQ_LDS_BANK_CONFLICT).
template <bool WRITE_BF16>
__global__ __launch_bounds__(256) void gin_fused(
    const unsigned short* __restrict__ xin,
    const unsigned* __restrict__ gcur, const unsigned* __restrict__ elog,
    const unsigned short* __restrict__ w1t, const float* __restrict__ b1,
    const unsigned short* __restrict__ w2t, const float* __restrict__ b2,
    float* __restrict__ out_f, unsigned short* __restrict__ out_b, int n_nodes)
{
    __shared__ float          acc[64][68];   // 17 KB f32 accumulator
    __shared__ unsigned short st [64][72];   // tanh intermediate (bf16)
    __shared__ unsigned short sw1[64][72];
    __shared__ unsigned short sw2[64][72];

    const int g    = blockIdx.x;
    const int t    = threadIdx.x;
    const int lane = t & 63;
    const int wv   = t >> 6;

    // P0a: stage weights
    for (int c = t; c < 512; c += 256) {
        int row = c >> 3, c8 = (c & 7) << 3;
        *(uint4*)&sw1[row][c8] = *(const uint4*)(w1t + row * D + c8);
        *(uint4*)&sw2[row][c8] = *(const uint4*)(w2t + row * D + c8);
    }
    // P0b: self rows -> f32 acc
    for (int c = t; c < 1024; c += 256) {
        int row = c >> 4, seg = c & 15;
        uint2 v = *(const uint2*)(xin + (size_t)(g * 64 + row) * D + seg * 4);
        float4 f;
        f.x = bf_lo(v.x); f.y = bf_hi(v.x); f.z = bf_lo(v.y); f.w = bf_hi(v.y);
        *(float4*)&acc[row][seg * 4] = f;
    }
    int cnt = (int)gcur[g]; if (cnt > LSLOT) cnt = LSLOT;
    __syncthreads();

    // P1: edge streaming
    const int eo = lane >> 4;       // edge slot 0..3 within wave
    const int el = lane & 15;       // feature segment 0..15 (4 feats each)
    for (int i0 = wv * 4; i0 < cnt; i0 += 16) {
        int i = i0 + eo;
        if (i < cnt) {
            unsigned v = elog[(size_t)g * LSLOT + i];
            int dl = (v >> 16) & 63;           // dst local (slices are 64-aligned)
            int s  = (int)(v & 0xffffu);       // src (n_nodes < 65536)
            uint2 r = *(const uint2*)(xin + (size_t)s * D + el * 4);
            atomicAdd(&acc[dl][el * 4 + 0], bf_lo(r.x));
            atomicAdd(&acc[dl][el * 4 + 1], bf_hi(r.x));
            atomicAdd(&acc[dl][el * 4 + 2], bf_lo(r.y));
            atomicAdd(&acc[dl][el * 4 + 3], bf_hi(r.y));
        }
    }
    __syncthreads();

    // P2: dense MFMA pipeline
    const int quad = lane >> 4;
    const int col  = lane & 15;
    const int arow = 16 * wv + col;
    const int koff = quad << 3;

    short8 a0, a1;
    {
        float4 f0 = *(const float4*)&acc[arow][koff];
        float4 f1 = *(const float4*)&acc[arow][koff + 4];
        float4 g0 = *(const float4*)&acc[arow][32 + koff];
        float4 g1 = *(const float4*)&acc[arow][32 + koff + 4];
        a0[0] = (short)f2bf(f0.x); a0[1] = (short)f2bf(f0.y);
        a0[2] = (short)f2bf(f0.z); a0[3] = (short)f2bf(f0.w);
        a0[4] = (short)f2bf(f1.x); a0[5] = (short)f2bf(f1.y);
        a0[6] = (short)f2bf(f1.z); a0[7] = (short)f2bf(f1.w);
        a1[0] = (short)f2bf(g0.x); a1[1] = (short)f2bf(g0.y);
        a1[2] = (short)f2bf(g0.z); a1[3] = (short)f2bf(g0.w);
        a1[4] = (short)f2bf(g1.x); a1[5] = (short)f2bf(g1.y);
        a1[6] = (short)f2bf(g1.z); a1[7] = (short)f2bf(g1.w);
    }

    #pragma unroll
    for (int nt = 0; nt < 4; ++nt) {
        int n = (nt << 4) + col;
        short8 bw0 = *(const short8*)&sw1[n][koff];
        short8 bw1 = *(const short8*)&sw1[n][32 + koff];
        float bv = b1[n];
        f32x4 c = {bv, bv, bv, bv};
        c = __builtin_amdgcn_mfma_f32_16x16x32_bf16(a0, bw0, c, 0, 0, 0);
        c = __builtin_amdgcn_mfma_f32_16x16x32_bf16(a1, bw1, c, 0, 0, 0);
        #pragma unroll
        for (int r = 0; r < 4; ++r)
            st[16 * wv + (quad << 2) + r][n] = f2bf(tanhf(c[r]));
    }
    // no __syncthreads: each wave reads back exactly the rows it wrote

    short8 p0 = *(const short8*)&st[arow][koff];
    short8 p1 = *(const short8*)&st[arow][32 + koff];

    #pragma unroll
    for (int nt = 0; nt < 4; ++nt) {
        int n = (nt << 4) + col;
        short8 bw0 = *(const short8*)&sw2[n][koff];
        short8 bw1 = *(const short8*)&sw2[n][32 + koff];
        float bv = b2[n];
        f32x4 c = {bv, bv, bv, bv};
        c = __builtin_amdgcn_mfma_f32_16x16x32_bf16(p0, bw0, c, 0, 0, 0);
        c = __builtin_amdgcn_mfma_f32_16x16x32_bf16(p1, bw1, c, 0, 0, 0);
        #pragma unroll
        for (int r = 0; r < 4; ++r) {
            int row = g * 64 + 16 * wv + (quad << 2) + r;
            if (WRITE_BF16) {
                out_b[(size_t)row * D + n] = f2bf(c[r]);   // x1b sized n_pad
            } else if (row < n_nodes) {
                out_f[(size_t)row * D + n] = c[r];
            }
        }
    }
}

extern "C" void kernel_launch(void* const* d_in, const int* in_sizes, int n_in,
                              void* d_out, int out_size, void* d_ws, size_t ws_size,
                              hipStream_t stream)
{
    const float* x    = (const float*)d_in[0];
    const int*   src  = (const int*)  d_in[1];
    const int*   dst  = (const int*)  d_in[2];
    const float* w1_0 = (const float*)d_in[3];
    const float* b1_0 = (const float*)d_in[4];
    const float* w2_0 = (const float*)d_in[5];
    const float* b2_0 = (const float*)d_in[6];
    const float* w1_1 = (const float*)d_in[7];
    const float* b1_1 = (const float*)d_in[8];
    const float* w2_1 = (const float*)d_in[9];
    const float* b2_1 = (const float*)d_in[10];
    float* out = (float*)d_out;

    const int n_nodes = in_sizes[0] / D;        // 50000
    const int n_edges = in_sizes[1];            // 800000
    const int n_pad   = (n_nodes + 63) & ~63;   // 50048
    const int S       = n_pad >> 6;             // 782 slices of 64 nodes

    // ws: gcur (u32[S]) | elog (u32[S*LSLOT]) | xb | x1b | wt   (bf16 after elog)
    unsigned*       gcur = (unsigned*)d_ws;
    unsigned*       elog = gcur + S;
    unsigned short* xb   = (unsigned short*)(elog + (size_t)S * LSLOT);
    unsigned short* x1b  = xb  + (size_t)n_pad * D;
    unsigned short* wt   = x1b + (size_t)n_pad * D;

    const int n4  = n_nodes * D / 4;             // 800000
    const int n4p = n_pad * D / 4;               // 800768 (pad rows zeroed)
    const int ncb = (n4p + 255) / 256;
    const int nsb = (n_edges + ACH - 1) / ACH;   // 128 slice-scatter blocks

    hipMemsetAsync(gcur, 0, (size_t)S * sizeof(unsigned), stream);
    prep_scatter_kernel<<<nsb + ncb + 64, 256, 0, stream>>>(
        src, dst, gcur, elog, n_edges, S, nsb,
        x, xb, n4, n4p, ncb,
        w1_0, w2_0, w1_1, w2_1, wt);

    // layer 0: fused aggregate + MLP -> x1b (bf16)
    gin_fused<true><<<S, 256, 0, stream>>>(
        xb, gcur, elog, wt, b1_0, wt + 4096, b2_0, nullptr, x1b, n_nodes);
    // layer 1: fused aggregate + MLP -> out (f32)
    gin_fused<false><<<S, 256, 0, stream>>>(
        x1b, gcur, elog, wt + 8192, b1_1, wt + 12288, b2_1, out, nullptr, n_nodes);
}

// Round 4
// 181.943 us; speedup vs baseline: 4.3539x; 4.3539x over previous
//
#include <hip/hip_runtime.h>

#define D 64
#define CAP 56     // per-node bucket capacity; P(Poisson(16) >= 56) ~ 1e-13
#define ACH 6250   // edges per slice-scatter block
#define LSLOT 3584 // per-slice edge-log capacity

typedef __attribute__((ext_vector_type(8))) short short8;   // 8 bf16 (4 VGPRs)
typedef __attribute__((ext_vector_type(4))) float f32x4;

__device__ __forceinline__ unsigned short f2bf(float f) {
    unsigned u = __float_as_uint(f);
    u = (u + 0x7fff + ((u >> 16) & 1)) >> 16;   // RNE
    return (unsigned short)u;
}
__device__ __forceinline__ float bf_lo(unsigned u) { return __uint_as_float(u << 16); }
__device__ __forceinline__ float bf_hi(unsigned u) { return __uint_as_float(u & 0xffff0000u); }

// R14 (kept): slice-scatter — each block bins its 6250-edge chunk by 64-node
// slice in LDS (LDS atomics + prefix-sum), reserves per-slice global ranges
// with ONE atomic per (block,slice) (~100k total vs 800k per-edge), appends
// slice-sorted packed (dst16|src16) edges to a per-slice edge log.
// Block roles in one launch (independent work, co-resident):
//  [0, nsb)            : slice-scatter
//  [nsb, nsb+ncb)      : convert  — x fp32 -> xb bf16 (pad rows zeroed)
//  [nsb+ncb, +64)      : prep     — 4 weight mats -> bf16 transposed
__global__ __launch_bounds__(256) void prep_scatter_kernel(
    const int* __restrict__ src, const int* __restrict__ dst,
    unsigned* __restrict__ gcur, unsigned* __restrict__ elog,
    int n_edges, int S, int nsb,
    const float* __restrict__ x, unsigned short* __restrict__ xb,
    int n4, int n4p, int ncb,
    const float* __restrict__ w1_0, const float* __restrict__ w2_0,
    const float* __restrict__ w1_1, const float* __restrict__ w2_1,
    unsigned short* __restrict__ wt)
{
    __shared__ int cnt[784], start[784], cur[784], gb[784];
    __shared__ int wsum[4];
    __shared__ unsigned reorder[6272];

    const int b   = blockIdx.x;
    const int tid = threadIdx.x;

    if (b < nsb) {
        const int e0 = b * ACH;
        const int nE = (n_edges - e0 < ACH) ? (n_edges - e0) : ACH;

        for (int j = tid; j < 784; j += 256) cnt[j] = 0;
        __syncthreads();

        for (int i = tid; i < nE; i += 256)
            atomicAdd(&cnt[dst[e0 + i] >> 6], 1);
        __syncthreads();

        {   // exclusive prefix over cnt[0..784)
            int t4 = tid * 4;
            int c0 = 0, c1 = 0, c2 = 0, c3 = 0;
            if (t4 < 784) { c0 = cnt[t4]; c1 = cnt[t4+1]; c2 = cnt[t4+2]; c3 = cnt[t4+3]; }
            int lsum = c0 + c1 + c2 + c3;
            int lane = tid & 63, wv = tid >> 6;
            int xs = lsum;
            #pragma unroll
            for (int o = 1; o < 64; o <<= 1) {
                int y = __shfl_up(xs, o, 64);
                if (lane >= o) xs += y;
            }
            if (lane == 63) wsum[wv] = xs;
            __syncthreads();
            int wo = 0;
            for (int w = 0; w < wv; ++w) wo += wsum[w];
            int excl = wo + xs - lsum;
            if (t4 < 784) {
                start[t4]   = excl;                cur[t4]   = excl;
                start[t4+1] = excl + c0;           cur[t4+1] = excl + c0;
                start[t4+2] = excl + c0 + c1;      cur[t4+2] = excl + c0 + c1;
                start[t4+3] = excl + c0 + c1 + c2; cur[t4+3] = excl + c0 + c1 + c2;
            }
        }
        __syncthreads();

        for (int j = tid; j < S; j += 256) {
            int c = cnt[j];
            gb[j] = c ? (int)atomicAdd(&gcur[j], (unsigned)c) : 0;
        }

        for (int i = tid; i < nE; i += 256) {
            int d = dst[e0 + i];
            int s = src[e0 + i];
            int r = atomicAdd(&cur[d >> 6], 1);
            reorder[r] = ((unsigned)d << 16) | (unsigned)s;
        }
        __syncthreads();

        for (int i = tid; i < nE; i += 256) {
            unsigned v = reorder[i];
            int sl  = v >> 22;                 // dst >> 6
            int idx = gb[sl] + (i - start[sl]);
            if (idx < LSLOT) elog[(size_t)sl * LSLOT + idx] = v;
        }
    } else if (b < nsb + ncb) {
        int i = (b - nsb) * 256 + tid;
        if (i < n4) {
            f32x4 v = __builtin_nontemporal_load((const f32x4*)(x + (size_t)i * 4));
            ushort4 o;
            o.x = f2bf(v.x); o.y = f2bf(v.y); o.z = f2bf(v.z); o.w = f2bf(v.w);
            *(ushort4*)(xb + (size_t)i * 4) = o;
        } else if (i < n4p) {
            *(ushort4*)(xb + (size_t)i * 4) = make_ushort4(0, 0, 0, 0);  // pad rows
        }
    } else {
        int i = (b - nsb - ncb) * 256 + tid;   // 0..16383
        int m = i >> 12, r = i & 4095;
        int n = r >> 6, k = r & 63;
        const float* w = (m == 0) ? w1_0 : (m == 1) ? w2_0 : (m == 2) ? w1_1 : w2_1;
        wt[i] = f2bf(w[k * 64 + n]);
    }
}

// R14 (kept): one block per 64-node slice. Reads the slice's edge log, builds
// per-node buckets in LDS (LDS atomics only), writes deg + buf out fully
// coalesced. Unused bucket slots zeroed (masked reads then hit node 0).
__global__ __launch_bounds__(256) void bucketize_kernel(
    const unsigned* __restrict__ gcur, const unsigned* __restrict__ elog,
    int* __restrict__ deg, unsigned short* __restrict__ buf)
{
    __shared__ int sdeg[64];
    __shared__ unsigned short sbuf[64][CAP];   // 7168 B

    const int g   = blockIdx.x;
    const int tid = threadIdx.x;

    unsigned* zb = (unsigned*)&sbuf[0][0];
    for (int i = tid; i < 64 * CAP / 2; i += 256) zb[i] = 0;
    if (tid < 64) sdeg[tid] = 0;
    int cnt = (int)gcur[g]; if (cnt > LSLOT) cnt = LSLOT;
    __syncthreads();

    for (int i = tid; i < cnt; i += 256) {
        unsigned v = elog[(size_t)g * LSLOT + i];
        int dl = (v >> 16) & 63;
        int p  = atomicAdd(&sdeg[dl], 1);
        if (p < CAP) sbuf[dl][p] = (unsigned short)(v & 0xffffu);
    }
    __syncthreads();

    const unsigned* sb = (const unsigned*)&sbuf[0][0];
    unsigned* gbuf = (unsigned*)(buf + (size_t)g * 64 * CAP);
    for (int i = tid; i < 64 * CAP / 2; i += 256) gbuf[i] = sb[i];
    if (tid < 64) deg[g * 64 + tid] = sdeg[tid];
}

// R16: fused gather+dense, one block per slice (64 nodes, 4 waves).
// Gather keeps R12's parallel engine VERBATIM (per-node ownership, 8 slots x
// 16B independent loads, masked FMA, shuffle-reduce — NO atomics; R15's LDS-
// atomic chain was the 346us disaster). Wave wv gathers its own 16 nodes
// (unroll 2 for MLP) into LDS accb rows; those are exactly the A-fragment rows
// it feeds to MFMA, so no barrier between gather and dense. One __syncthreads
// total (weight stage). Load trimming: groups 0-1 unconditional (16 rows),
// group 2 iff dd>16, tail iff dd>24 (both wave-uniform) -> ~20 rows avg vs 24.
template <bool WRITE_BF16>
__global__ __launch_bounds__(256) void gin_fused(
    const unsigned short* __restrict__ xin,
    const int* __restrict__ deg, const unsigned short* __restrict__ buf,
    const unsigned short* __restrict__ w1t, const float* __restrict__ b1,
    const unsigned short* __restrict__ w2t, const float* __restrict__ b2,
    float* __restrict__ out_f, unsigned short* __restrict__ out_b, int n_nodes)
{
    __shared__ __align__(16) unsigned short accb[64][72];  // aggregated rows (bf16)
    __shared__ __align__(16) unsigned short st  [64][72];  // tanh intermediate
    __shared__ __align__(16) unsigned short sw1 [64][72];
    __shared__ __align__(16) unsigned short sw2 [64][72];

    const int g    = blockIdx.x;
    const int t    = threadIdx.x;
    const int lane = t & 63;
    const int wv   = t >> 6;
    const int slot = lane >> 3;        // 0..7
    const int fc   = (lane & 7) << 3;  // bf16 offset 0,8,...,56 (16B per lane)

    // stage weights (consumed after the single barrier below)
    for (int c = t; c < 512; c += 256) {
        int row = c >> 3, c8 = (c & 7) << 3;
        *(uint4*)&sw1[row][c8] = *(const uint4*)(w1t + row * D + c8);
        *(uint4*)&sw2[row][c8] = *(const uint4*)(w2t + row * D + c8);
    }

    // gather: wave wv owns local nodes 16wv..16wv+15
    #pragma unroll 2
    for (int j = 0; j < 16; ++j) {
        const int nl = (wv << 4) + j;
        const int n  = (g << 6) + nl;

        int my_idx = buf[(size_t)n * CAP + (lane < CAP ? lane : CAP - 1)];
        int dd = deg[n];
        dd = dd < CAP ? dd : CAP;

        uint4 u = make_uint4(0u, 0u, 0u, 0u);
        if (slot == 0) u = *(const uint4*)(xin + (size_t)n * D + fc);

        int s[7];
        #pragma unroll
        for (int gg = 0; gg < 7; ++gg) s[gg] = __shfl(my_idx, (gg << 3) + slot);

        uint4 v0 = *(const uint4*)(xin + (size_t)s[0] * D + fc);
        uint4 v1 = *(const uint4*)(xin + (size_t)s[1] * D + fc);

        float a[8] = {0.f, 0.f, 0.f, 0.f, 0.f, 0.f, 0.f, 0.f};

        if (dd > 16) {   // wave-uniform, ~43% of nodes
            uint4 v2 = *(const uint4*)(xin + (size_t)s[2] * D + fc);
            float m2 = (slot + 16 < dd) ? 1.0f : 0.0f;
            a[0] += bf_lo(v2.x) * m2; a[1] += bf_hi(v2.x) * m2;
            a[2] += bf_lo(v2.y) * m2; a[3] += bf_hi(v2.y) * m2;
            a[4] += bf_lo(v2.z) * m2; a[5] += bf_hi(v2.z) * m2;
            a[6] += bf_lo(v2.w) * m2; a[7] += bf_hi(v2.w) * m2;
        }
        if (dd > 24) {   // wave-uniform, ~2% of nodes
            #pragma unroll
            for (int gg = 3; gg < 7; ++gg) {
                uint4 v = *(const uint4*)(xin + (size_t)s[gg] * D + fc);
                float m = ((gg << 3) + slot) < dd ? 1.0f : 0.0f;
                a[0] += bf_lo(v.x) * m; a[1] += bf_hi(v.x) * m;
                a[2] += bf_lo(v.y) * m; a[3] += bf_hi(v.y) * m;
                a[4] += bf_lo(v.z) * m; a[5] += bf_hi(v.z) * m;
                a[6] += bf_lo(v.w) * m; a[7] += bf_hi(v.w) * m;
            }
        }
        {
            float m0 = (slot     < dd) ? 1.0f : 0.0f;
            float m1 = (slot + 8 < dd) ? 1.0f : 0.0f;
            a[0] += bf_lo(v0.x) * m0 + bf_lo(v1.x) * m1 + bf_lo(u.x);
            a[1] += bf_hi(v0.x) * m0 + bf_hi(v1.x) * m1 + bf_hi(u.x);
            a[2] += bf_lo(v0.y) * m0 + bf_lo(v1.y) * m1 + bf_lo(u.y);
            a[3] += bf_hi(v0.y) * m0 + bf_hi(v1.y) * m1 + bf_hi(u.y);
            a[4] += bf_lo(v0.z) * m0 + bf_lo(v1.z) * m1 + bf_lo(u.z);
            a[5] += bf_hi(v0.z) * m0 + bf_hi(v1.z) * m1 + bf_hi(u.z);
            a[6] += bf_lo(v0.w) * m0 + bf_lo(v1.w) * m1 + bf_lo(u.w);
            a[7] += bf_hi(v0.w) * m0 + bf_hi(v1.w) * m1 + bf_hi(u.w);
        }

        #pragma unroll
        for (int m = 8; m <= 32; m <<= 1) {
            #pragma unroll
            for (int q = 0; q < 8; ++q) a[q] += __shfl_xor(a[q], m);
        }
        if (slot == 0) {
            uint4 o;
            o.x = (unsigned)f2bf(a[0]) | ((unsigned)f2bf(a[1]) << 16);
            o.y = (unsigned)f2bf(a[2]) | ((unsigned)f2bf(a[3]) << 16);
            o.z = (unsigned)f2bf(a[4]) | ((unsigned)f2bf(a[5]) << 16);
            o.w = (unsigned)f2bf(a[6]) | ((unsigned)f2bf(a[7]) << 16);
            *(uint4*)&accb[nl][fc] = o;
        }
    }
    __syncthreads();   // weights visible; accb rows are wave-private

    // dense MFMA pipeline (verified): wave reads back exactly its own rows
    const int quad = lane >> 4;
    const int col  = lane & 15;
    const int arow = (wv << 4) + col;
    const int koff = quad << 3;

    short8 a0 = *(const short8*)&accb[arow][koff];
    short8 a1 = *(const short8*)&accb[arow][32 + koff];

    #pragma unroll
    for (int nt = 0; nt < 4; ++nt) {
        int n = (nt << 4) + col;
        short8 bw0 = *(const short8*)&sw1[n][koff];
        short8 bw1 = *(const short8*)&sw1[n][32 + koff];
        float bv = b1[n];
        f32x4 c = {bv, bv, bv, bv};
        c = __builtin_amdgcn_mfma_f32_16x16x32_bf16(a0, bw0, c, 0, 0, 0);
        c = __builtin_amdgcn_mfma_f32_16x16x32_bf16(a1, bw1, c, 0, 0, 0);
        #pragma unroll
        for (int r = 0; r < 4; ++r)
            st[(wv << 4) + (quad << 2) + r][n] = f2bf(tanhf(c[r]));
    }
    // no __syncthreads: each wave reads back exactly the rows it wrote

    short8 p0 = *(const short8*)&st[arow][koff];
    short8 p1 = *(const short8*)&st[arow][32 + koff];

    #pragma unroll
    for (int nt = 0; nt < 4; ++nt) {
        int n = (nt << 4) + col;
        short8 bw0 = *(const short8*)&sw2[n][koff];
        short8 bw1 = *(const short8*)&sw2[n][32 + koff];
        float bv = b2[n];
        f32x4 c = {bv, bv, bv, bv};
        c = __builtin_amdgcn_mfma_f32_16x16x32_bf16(p0, bw0, c, 0, 0, 0);
        c = __builtin_amdgcn_mfma_f32_16x16x32_bf16(p1, bw1, c, 0, 0, 0);
        #pragma unroll
        for (int r = 0; r < 4; ++r) {
            int row = (g << 6) + (wv << 4) + (quad << 2) + r;
            if (WRITE_BF16) {
                out_b[(size_t)row * D + n] = f2bf(c[r]);   // x1b sized n_pad
            } else if (row < n_nodes) {
                out_f[(size_t)row * D + n] = c[r];
            }
        }
    }
}

extern "C" void kernel_launch(void* const* d_in, const int* in_sizes, int n_in,
                              void* d_out, int out_size, void* d_ws, size_t ws_size,
                              hipStream_t stream)
{
    const float* x    = (const float*)d_in[0];
    const int*   src  = (const int*)  d_in[1];
    const int*   dst  = (const int*)  d_in[2];
    const float* w1_0 = (const float*)d_in[3];
    const float* b1_0 = (const float*)d_in[4];
    const float* w2_0 = (const float*)d_in[5];
    const float* b2_0 = (const float*)d_in[6];
    const float* w1_1 = (const float*)d_in[7];
    const float* b1_1 = (const float*)d_in[8];
    const float* w2_1 = (const float*)d_in[9];
    const float* b2_1 = (const float*)d_in[10];
    float* out = (float*)d_out;

    const int n_nodes = in_sizes[0] / D;        // 50000
    const int n_edges = in_sizes[1];            // 800000
    const int n_pad   = (n_nodes + 63) & ~63;   // 50048
    const int S       = n_pad >> 6;             // 782 slices of 64 nodes

    // ws: gcur (u32[S]) | elog | deg | buf | xb | x1b | wt
    unsigned*       gcur = (unsigned*)d_ws;
    unsigned*       elog = gcur + S;
    int*            deg  = (int*)(elog + (size_t)S * LSLOT);
    unsigned short* buf  = (unsigned short*)(deg + n_pad);
    unsigned short* xb   = buf + (size_t)n_pad * CAP;
    unsigned short* x1b  = xb  + (size_t)n_pad * D;
    unsigned short* wt   = x1b + (size_t)n_pad * D;

    const int n4  = n_nodes * D / 4;             // 800000
    const int n4p = n_pad * D / 4;               // 800768 (pad rows zeroed)
    const int ncb = (n4p + 255) / 256;
    const int nsb = (n_edges + ACH - 1) / ACH;   // 128 slice-scatter blocks

    hipMemsetAsync(gcur, 0, (size_t)S * sizeof(unsigned), stream);
    prep_scatter_kernel<<<nsb + ncb + 64, 256, 0, stream>>>(
        src, dst, gcur, elog, n_edges, S, nsb,
        x, xb, n4, n4p, ncb,
        w1_0, w2_0, w1_1, w2_1, wt);
    bucketize_kernel<<<S, 256, 0, stream>>>(gcur, elog, deg, buf);

    // layer 0: fused aggregate + MLP -> x1b (bf16)
    gin_fused<true><<<S, 256, 0, stream>>>(
        xb, deg, buf, wt, b1_0, wt + 4096, b2_0, nullptr, x1b, n_nodes);
    // layer 1: fused aggregate + MLP -> out (f32)
    gin_fused<false><<<S, 256, 0, stream>>>(
        x1b, deg, buf, wt + 8192, b1_1, wt + 12288, b2_1, out, nullptr, n_nodes);
}

// Round 5
// 172.534 us; speedup vs baseline: 4.5914x; 1.0545x over previous
//
#include <hip/hip_runtime.h>

#define D 64
#define CAP 56     // per-node bucket capacity; P(Poisson(16) >= 56) ~ 1e-13
#define ACH 6250   // edges per slice-scatter block
#define LSLOT 3584 // per-slice edge-log capacity

typedef __attribute__((ext_vector_type(8))) short short8;   // 8 bf16 (4 VGPRs)
typedef __attribute__((ext_vector_type(4))) float f32x4;

__device__ __forceinline__ unsigned short f2bf(float f) {
    unsigned u = __float_as_uint(f);
    u = (u + 0x7fff + ((u >> 16) & 1)) >> 16;   // RNE
    return (unsigned short)u;
}
__device__ __forceinline__ float bf_lo(unsigned u) { return __uint_as_float(u << 16); }
__device__ __forceinline__ float bf_hi(unsigned u) { return __uint_as_float(u & 0xffff0000u); }

// R14 (kept): slice-scatter — each block bins its 6250-edge chunk by 64-node
// slice in LDS (LDS atomics + prefix-sum), reserves per-slice global ranges
// with ONE atomic per (block,slice) (~100k total vs 800k per-edge), appends
// slice-sorted packed (dst16|src16) edges to a per-slice edge log.
// Block roles in one launch (independent work, co-resident):
//  [0, nsb)            : slice-scatter
//  [nsb, nsb+ncb)      : convert  — x fp32 -> xb bf16 (pad rows zeroed)
//  [nsb+ncb, +64)      : prep     — 4 weight mats -> bf16 transposed
__global__ __launch_bounds__(256) void prep_scatter_kernel(
    const int* __restrict__ src, const int* __restrict__ dst,
    unsigned* __restrict__ gcur, unsigned* __restrict__ elog,
    int n_edges, int S, int nsb,
    const float* __restrict__ x, unsigned short* __restrict__ xb,
    int n4, int n4p, int ncb,
    const float* __restrict__ w1_0, const float* __restrict__ w2_0,
    const float* __restrict__ w1_1, const float* __restrict__ w2_1,
    unsigned short* __restrict__ wt)
{
    __shared__ int cnt[784], start[784], cur[784], gb[784];
    __shared__ int wsum[4];
    __shared__ unsigned reorder[6272];

    const int b   = blockIdx.x;
    const int tid = threadIdx.x;

    if (b < nsb) {
        const int e0 = b * ACH;
        const int nE = (n_edges - e0 < ACH) ? (n_edges - e0) : ACH;

        for (int j = tid; j < 784; j += 256) cnt[j] = 0;
        __syncthreads();

        for (int i = tid; i < nE; i += 256)
            atomicAdd(&cnt[dst[e0 + i] >> 6], 1);
        __syncthreads();

        {   // exclusive prefix over cnt[0..784)
            int t4 = tid * 4;
            int c0 = 0, c1 = 0, c2 = 0, c3 = 0;
            if (t4 < 784) { c0 = cnt[t4]; c1 = cnt[t4+1]; c2 = cnt[t4+2]; c3 = cnt[t4+3]; }
            int lsum = c0 + c1 + c2 + c3;
            int lane = tid & 63, wv = tid >> 6;
            int xs = lsum;
            #pragma unroll
            for (int o = 1; o < 64; o <<= 1) {
                int y = __shfl_up(xs, o, 64);
                if (lane >= o) xs += y;
            }
            if (lane == 63) wsum[wv] = xs;
            __syncthreads();
            int wo = 0;
            for (int w = 0; w < wv; ++w) wo += wsum[w];
            int excl = wo + xs - lsum;
            if (t4 < 784) {
                start[t4]   = excl;                cur[t4]   = excl;
                start[t4+1] = excl + c0;           cur[t4+1] = excl + c0;
                start[t4+2] = excl + c0 + c1;      cur[t4+2] = excl + c0 + c1;
                start[t4+3] = excl + c0 + c1 + c2; cur[t4+3] = excl + c0 + c1 + c2;
            }
        }
        __syncthreads();

        for (int j = tid; j < S; j += 256) {
            int c = cnt[j];
            gb[j] = c ? (int)atomicAdd(&gcur[j], (unsigned)c) : 0;
        }

        for (int i = tid; i < nE; i += 256) {
            int d = dst[e0 + i];
            int s = src[e0 + i];
            int r = atomicAdd(&cur[d >> 6], 1);
            reorder[r] = ((unsigned)d << 16) | (unsigned)s;
        }
        __syncthreads();

        for (int i = tid; i < nE; i += 256) {
            unsigned v = reorder[i];
            int sl  = v >> 22;                 // dst >> 6
            int idx = gb[sl] + (i - start[sl]);
            if (idx < LSLOT) elog[(size_t)sl * LSLOT + idx] = v;
        }
    } else if (b < nsb + ncb) {
        int i = (b - nsb) * 256 + tid;
        if (i < n4) {
            f32x4 v = __builtin_nontemporal_load((const f32x4*)(x + (size_t)i * 4));
            ushort4 o;
            o.x = f2bf(v.x); o.y = f2bf(v.y); o.z = f2bf(v.z); o.w = f2bf(v.w);
            *(ushort4*)(xb + (size_t)i * 4) = o;
        } else if (i < n4p) {
            *(ushort4*)(xb + (size_t)i * 4) = make_ushort4(0, 0, 0, 0);  // pad rows
        }
    } else {
        int i = (b - nsb - ncb) * 256 + tid;   // 0..16383
        int m = i >> 12, r = i & 4095;
        int n = r >> 6, k = r & 63;
        const float* w = (m == 0) ? w1_0 : (m == 1) ? w2_0 : (m == 2) ? w1_1 : w2_1;
        wt[i] = f2bf(w[k * 64 + n]);
    }
}

// R14 (kept): one block per 64-node slice. Reads the slice's edge log, builds
// per-node buckets in LDS (LDS atomics only), writes deg + buf out fully
// coalesced. Unused bucket slots zeroed (masked reads then hit node 0).
__global__ __launch_bounds__(256) void bucketize_kernel(
    const unsigned* __restrict__ gcur, const unsigned* __restrict__ elog,
    int* __restrict__ deg, unsigned short* __restrict__ buf)
{
    __shared__ int sdeg[64];
    __shared__ unsigned short sbuf[64][CAP];   // 7168 B

    const int g   = blockIdx.x;
    const int tid = threadIdx.x;

    unsigned* zb = (unsigned*)&sbuf[0][0];
    for (int i = tid; i < 64 * CAP / 2; i += 256) zb[i] = 0;
    if (tid < 64) sdeg[tid] = 0;
    int cnt = (int)gcur[g]; if (cnt > LSLOT) cnt = LSLOT;
    __syncthreads();

    for (int i = tid; i < cnt; i += 256) {
        unsigned v = elog[(size_t)g * LSLOT + i];
        int dl = (v >> 16) & 63;
        int p  = atomicAdd(&sdeg[dl], 1);
        if (p < CAP) sbuf[dl][p] = (unsigned short)(v & 0xffffu);
    }
    __syncthreads();

    const unsigned* sb = (const unsigned*)&sbuf[0][0];
    unsigned* gbuf = (unsigned*)(buf + (size_t)g * 64 * CAP);
    for (int i = tid; i < 64 * CAP / 2; i += 256) gbuf[i] = sb[i];
    if (tid < 64) deg[g * 64 + tid] = sdeg[tid];
}

// agg[n] = xb[n] + sum_{s in bucket[n]} xb[s]  (bf16 in, fp32 acc, bf16 out).
// R12 engine (50k waves, 1 node/wave, zero atomics) — proven twice that this
// parallelism is the asset (R15/R16 fusions both lost to it).
// R17: degree-exact group loading. Poisson(16): P(dd>16)=0.43, P(dd>24)=0.02.
// Groups 0-1 (16 rows) unconditional; group 2 only if dd>16; tail if dd>24.
// Both branches wave-uniform. Expected rows 25.3 -> ~20.7 (-18% random reads).
__global__ __launch_bounds__(256) void gather_kernel(
    const unsigned short* __restrict__ xb, const int* __restrict__ deg,
    const unsigned short* __restrict__ buf, unsigned short* __restrict__ aggb)
{
    const int tid  = threadIdx.x;
    const int lane = tid & 63;
    const int wave = tid >> 6;
    const int n    = blockIdx.x * 4 + wave;

    const int slot = lane >> 3;        // 0..7
    const int fc   = (lane & 7) << 3;  // bf16 offset 0,8,...,56 (16B per lane)

    int my_idx = buf[(size_t)n * CAP + (lane < CAP ? lane : CAP - 1)];
    int dd = deg[n];
    dd = dd < CAP ? dd : CAP;

    uint4 u = make_uint4(0u, 0u, 0u, 0u);
    if (slot == 0) u = *(const uint4*)(xb + (size_t)n * D + fc);

    int s[7];
    #pragma unroll
    for (int g = 0; g < 7; ++g) s[g] = __shfl(my_idx, (g << 3) + slot);

    // groups 0-1: unconditional back-to-back issue (16 rows)
    uint4 v0 = *(const uint4*)(xb + (size_t)s[0] * D + fc);
    uint4 v1 = *(const uint4*)(xb + (size_t)s[1] * D + fc);

    float a[8] = {0.f, 0.f, 0.f, 0.f, 0.f, 0.f, 0.f, 0.f};

    if (dd > 16) {   // wave-uniform, ~43% of nodes
        uint4 v2 = *(const uint4*)(xb + (size_t)s[2] * D + fc);
        float m2 = (slot + 16 < dd) ? 1.0f : 0.0f;
        a[0] += bf_lo(v2.x) * m2; a[1] += bf_hi(v2.x) * m2;
        a[2] += bf_lo(v2.y) * m2; a[3] += bf_hi(v2.y) * m2;
        a[4] += bf_lo(v2.z) * m2; a[5] += bf_hi(v2.z) * m2;
        a[6] += bf_lo(v2.w) * m2; a[7] += bf_hi(v2.w) * m2;
    }
    if (dd > 24) {   // wave-uniform, ~2% of nodes
        #pragma unroll
        for (int g = 3; g < 7; ++g) {
            uint4 v = *(const uint4*)(xb + (size_t)s[g] * D + fc);
            float m = ((g << 3) + slot) < dd ? 1.0f : 0.0f;
            a[0] += bf_lo(v.x) * m; a[1] += bf_hi(v.x) * m;
            a[2] += bf_lo(v.y) * m; a[3] += bf_hi(v.y) * m;
            a[4] += bf_lo(v.z) * m; a[5] += bf_hi(v.z) * m;
            a[6] += bf_lo(v.w) * m; a[7] += bf_hi(v.w) * m;
        }
    }

    {   // accumulate groups 0-1 (masked) + self
        float m0 = (slot     < dd) ? 1.0f : 0.0f;
        float m1 = (slot + 8 < dd) ? 1.0f : 0.0f;
        a[0] += bf_lo(v0.x) * m0 + bf_lo(v1.x) * m1 + bf_lo(u.x);
        a[1] += bf_hi(v0.x) * m0 + bf_hi(v1.x) * m1 + bf_hi(u.x);
        a[2] += bf_lo(v0.y) * m0 + bf_lo(v1.y) * m1 + bf_lo(u.y);
        a[3] += bf_hi(v0.y) * m0 + bf_hi(v1.y) * m1 + bf_hi(u.y);
        a[4] += bf_lo(v0.z) * m0 + bf_lo(v1.z) * m1 + bf_lo(u.z);
        a[5] += bf_hi(v0.z) * m0 + bf_hi(v1.z) * m1 + bf_hi(u.z);
        a[6] += bf_lo(v0.w) * m0 + bf_lo(v1.w) * m1 + bf_lo(u.w);
        a[7] += bf_hi(v0.w) * m0 + bf_hi(v1.w) * m1 + bf_hi(u.w);
    }

    #pragma unroll
    for (int m = 8; m <= 32; m <<= 1) {
        #pragma unroll
        for (int q = 0; q < 8; ++q) a[q] += __shfl_xor(a[q], m);
    }
    if (slot == 0) {
        uint4 o;
        o.x = (unsigned)f2bf(a[0]) | ((unsigned)f2bf(a[1]) << 16);
        o.y = (unsigned)f2bf(a[2]) | ((unsigned)f2bf(a[3]) << 16);
        o.z = (unsigned)f2bf(a[4]) | ((unsigned)f2bf(a[5]) << 16);
        o.w = (unsigned)f2bf(a[6]) | ((unsigned)f2bf(a[7]) << 16);
        *(uint4*)(aggb + (size_t)n * D + fc) = o;
    }
}

// out = tanh(h @ W1 + b1) @ W2 + b2 via mfma_f32_16x16x32_bf16.
// Block = 64 nodes x 64 feats, 4 waves; wave w owns node rows 16w..16w+15.
// C/D: col=lane&15, row=quad*4+reg (m89-verified). Wave-private tanh LDS
// round-trip between the matmuls -> no barrier. Rows padded to 72 bf16.
template <bool WRITE_BF16>
__global__ __launch_bounds__(256) void gin_dense_mfma(
    const unsigned short* __restrict__ hb, int n_nodes,
    const unsigned short* __restrict__ w1t, const float* __restrict__ b1,
    const unsigned short* __restrict__ w2t, const float* __restrict__ b2,
    float* __restrict__ out_f, unsigned short* __restrict__ out_b)
{
    __shared__ unsigned short sh [64][72];
    __shared__ unsigned short st [64][72];
    __shared__ unsigned short sw1[64][72];
    __shared__ unsigned short sw2[64][72];

    const int t    = threadIdx.x;
    const int lane = t & 63;
    const int wave = t >> 6;
    const int quad = lane >> 4;
    const int col  = lane & 15;
    const int nb   = blockIdx.x * 64;

    for (int c = t; c < 512; c += 256) {
        int row = c >> 3, c8 = (c & 7) << 3;
        *(uint4*)&sh [row][c8] = *(const uint4*)(hb  + (size_t)(nb + row) * D + c8);
        *(uint4*)&sw1[row][c8] = *(const uint4*)(w1t + row * D + c8);
        *(uint4*)&sw2[row][c8] = *(const uint4*)(w2t + row * D + c8);
    }
    __syncthreads();

    const int arow = 16 * wave + col;
    const int koff = quad << 3;

    short8 a0 = *(const short8*)&sh[arow][koff];
    short8 a1 = *(const short8*)&sh[arow][32 + koff];

    #pragma unroll
    for (int nt = 0; nt < 4; ++nt) {
        int n = (nt << 4) + col;
        short8 bw0 = *(const short8*)&sw1[n][koff];
        short8 bw1 = *(const short8*)&sw1[n][32 + koff];
        float bv = b1[n];
        f32x4 c = {bv, bv, bv, bv};
        c = __builtin_amdgcn_mfma_f32_16x16x32_bf16(a0, bw0, c, 0, 0, 0);
        c = __builtin_amdgcn_mfma_f32_16x16x32_bf16(a1, bw1, c, 0, 0, 0);
        #pragma unroll
        for (int r = 0; r < 4; ++r)
            st[16 * wave + (quad << 2) + r][n] = f2bf(tanhf(c[r]));
    }
    // no __syncthreads: each wave reads back exactly the rows it wrote

    short8 p0 = *(const short8*)&st[arow][koff];
    short8 p1 = *(const short8*)&st[arow][32 + koff];

    #pragma unroll
    for (int nt = 0; nt < 4; ++nt) {
        int n = (nt << 4) + col;
        short8 bw0 = *(const short8*)&sw2[n][koff];
        short8 bw1 = *(const short8*)&sw2[n][32 + koff];
        float bv = b2[n];
        f32x4 c = {bv, bv, bv, bv};
        c = __builtin_amdgcn_mfma_f32_16x16x32_bf16(p0, bw0, c, 0, 0, 0);
        c = __builtin_amdgcn_mfma_f32_16x16x32_bf16(p1, bw1, c, 0, 0, 0);
        #pragma unroll
        for (int r = 0; r < 4; ++r) {
            int row = nb + 16 * wave + (quad << 2) + r;
            if (WRITE_BF16) {
                out_b[(size_t)row * D + n] = f2bf(c[r]);   // x1b sized n_pad: no clamp
            } else if (row < n_nodes) {
                out_f[(size_t)row * D + n] = c[r];
            }
        }
    }
}

extern "C" void kernel_launch(void* const* d_in, const int* in_sizes, int n_in,
                              void* d_out, int out_size, void* d_ws, size_t ws_size,
                              hipStream_t stream)
{
    const float* x    = (const float*)d_in[0];
    const int*   src  = (const int*)  d_in[1];
    const int*   dst  = (const int*)  d_in[2];
    const float* w1_0 = (const float*)d_in[3];
    const float* b1_0 = (const float*)d_in[4];
    const float* w2_0 = (const float*)d_in[5];
    const float* b2_0 = (const float*)d_in[6];
    const float* w1_1 = (const float*)d_in[7];
    const float* b1_1 = (const float*)d_in[8];
    const float* w2_1 = (const float*)d_in[9];
    const float* b2_1 = (const float*)d_in[10];
    float* out = (float*)d_out;

    const int n_nodes = in_sizes[0] / D;        // 50000
    const int n_edges = in_sizes[1];            // 800000
    const int n_pad   = (n_nodes + 63) & ~63;   // 50048
    const int S       = n_pad >> 6;             // 782 slices of 64 nodes

    // ws: gcur (u32[S]) | elog | deg | buf | aggb | xb | x1b | wt
    unsigned*       gcur = (unsigned*)d_ws;
    unsigned*       elog = gcur + S;
    int*            deg  = (int*)(elog + (size_t)S * LSLOT);
    unsigned short* buf  = (unsigned short*)(deg + n_pad);
    unsigned short* aggb = buf  + (size_t)n_pad * CAP;
    unsigned short* xb   = aggb + (size_t)n_pad * D;
    unsigned short* x1b  = xb   + (size_t)n_pad * D;
    unsigned short* wt   = x1b  + (size_t)n_pad * D;

    const int n4  = n_nodes * D / 4;             // 800000
    const int n4p = n_pad * D / 4;               // 800768 (pad rows zeroed)
    const int ncb = (n4p + 255) / 256;
    const int nsb = (n_edges + ACH - 1) / ACH;   // 128 slice-scatter blocks

    hipMemsetAsync(gcur, 0, (size_t)S * sizeof(unsigned), stream);
    prep_scatter_kernel<<<nsb + ncb + 64, 256, 0, stream>>>(
        src, dst, gcur, elog, n_edges, S, nsb,
        x, xb, n4, n4p, ncb,
        w1_0, w2_0, w1_1, w2_1, wt);
    bucketize_kernel<<<S, 256, 0, stream>>>(gcur, elog, deg, buf);

    const int gather_blocks = n_pad / 4;      // 12512
    const int dense_blocks  = n_pad / 64;     // 782

    // layer 0
    gather_kernel<<<gather_blocks, 256, 0, stream>>>(xb, deg, buf, aggb);
    gin_dense_mfma<true><<<dense_blocks, 256, 0, stream>>>(
        aggb, n_nodes, wt, b1_0, wt + 4096, b2_0, nullptr, x1b);
    // layer 1
    gather_kernel<<<gather_blocks, 256, 0, stream>>>(x1b, deg, buf, aggb);
    gin_dense_mfma<false><<<dense_blocks, 256, 0, stream>>>(
        aggb, n_nodes, wt + 8192, b1_1, wt + 12288, b2_1, out, nullptr);
}

// Round 6
// 168.994 us; speedup vs baseline: 4.6875x; 1.0209x over previous
//
#include <hip/hip_runtime.h>

#define D 64
#define CAP 56     // per-node bucket capacity; P(Poisson(16) >= 56) ~ 1e-13
#define ACH 6250   // edges per slice-scatter block
#define LSLOT 3584 // per-slice edge-log capacity

typedef __attribute__((ext_vector_type(8))) short short8;   // 8 bf16 (4 VGPRs)
typedef __attribute__((ext_vector_type(4))) float f32x4;

__device__ __forceinline__ unsigned short f2bf(float f) {
    unsigned u = __float_as_uint(f);
    u = (u + 0x7fff + ((u >> 16) & 1)) >> 16;   // RNE
    return (unsigned short)u;
}
__device__ __forceinline__ float bf_lo(unsigned u) { return __uint_as_float(u << 16); }
__device__ __forceinline__ float bf_hi(unsigned u) { return __uint_as_float(u & 0xffff0000u); }

// R14 (kept): slice-scatter — each block bins its 6250-edge chunk by 64-node
// slice in LDS (LDS atomics + prefix-sum), reserves per-slice global ranges
// with ONE atomic per (block,slice) (~100k total vs 800k per-edge), appends
// slice-sorted packed (dst16|src16) edges to a per-slice edge log.
// Block roles in one launch (independent work, co-resident):
//  [0, nsb)            : slice-scatter
//  [nsb, nsb+ncb)      : convert  — x fp32 -> xb bf16 (pad rows zeroed)
//  [nsb+ncb, +64)      : prep     — 4 weight mats -> bf16 transposed
__global__ __launch_bounds__(256) void prep_scatter_kernel(
    const int* __restrict__ src, const int* __restrict__ dst,
    unsigned* __restrict__ gcur, unsigned* __restrict__ elog,
    int n_edges, int S, int nsb,
    const float* __restrict__ x, unsigned short* __restrict__ xb,
    int n4, int n4p, int ncb,
    const float* __restrict__ w1_0, const float* __restrict__ w2_0,
    const float* __restrict__ w1_1, const float* __restrict__ w2_1,
    unsigned short* __restrict__ wt)
{
    __shared__ int cnt[784], start[784], cur[784], gb[784];
    __shared__ int wsum[4];
    __shared__ unsigned reorder[6272];

    const int b   = blockIdx.x;
    const int tid = threadIdx.x;

    if (b < nsb) {
        const int e0 = b * ACH;
        const int nE = (n_edges - e0 < ACH) ? (n_edges - e0) : ACH;

        for (int j = tid; j < 784; j += 256) cnt[j] = 0;
        __syncthreads();

        for (int i = tid; i < nE; i += 256)
            atomicAdd(&cnt[dst[e0 + i] >> 6], 1);
        __syncthreads();

        {   // exclusive prefix over cnt[0..784)
            int t4 = tid * 4;
            int c0 = 0, c1 = 0, c2 = 0, c3 = 0;
            if (t4 < 784) { c0 = cnt[t4]; c1 = cnt[t4+1]; c2 = cnt[t4+2]; c3 = cnt[t4+3]; }
            int lsum = c0 + c1 + c2 + c3;
            int lane = tid & 63, wv = tid >> 6;
            int xs = lsum;
            #pragma unroll
            for (int o = 1; o < 64; o <<= 1) {
                int y = __shfl_up(xs, o, 64);
                if (lane >= o) xs += y;
            }
            if (lane == 63) wsum[wv] = xs;
            __syncthreads();
            int wo = 0;
            for (int w = 0; w < wv; ++w) wo += wsum[w];
            int excl = wo + xs - lsum;
            if (t4 < 784) {
                start[t4]   = excl;                cur[t4]   = excl;
                start[t4+1] = excl + c0;           cur[t4+1] = excl + c0;
                start[t4+2] = excl + c0 + c1;      cur[t4+2] = excl + c0 + c1;
                start[t4+3] = excl + c0 + c1 + c2; cur[t4+3] = excl + c0 + c1 + c2;
            }
        }
        __syncthreads();

        for (int j = tid; j < S; j += 256) {
            int c = cnt[j];
            gb[j] = c ? (int)atomicAdd(&gcur[j], (unsigned)c) : 0;
        }

        for (int i = tid; i < nE; i += 256) {
            int d = dst[e0 + i];
            int s = src[e0 + i];
            int r = atomicAdd(&cur[d >> 6], 1);
            reorder[r] = ((unsigned)d << 16) | (unsigned)s;
        }
        __syncthreads();

        for (int i = tid; i < nE; i += 256) {
            unsigned v = reorder[i];
            int sl  = v >> 22;                 // dst >> 6
            int idx = gb[sl] + (i - start[sl]);
            if (idx < LSLOT) elog[(size_t)sl * LSLOT + idx] = v;
        }
    } else if (b < nsb + ncb) {
        int i = (b - nsb) * 256 + tid;
        if (i < n4) {
            f32x4 v = __builtin_nontemporal_load((const f32x4*)(x + (size_t)i * 4));
            ushort4 o;
            o.x = f2bf(v.x); o.y = f2bf(v.y); o.z = f2bf(v.z); o.w = f2bf(v.w);
            *(ushort4*)(xb + (size_t)i * 4) = o;
        } else if (i < n4p) {
            *(ushort4*)(xb + (size_t)i * 4) = make_ushort4(0, 0, 0, 0);  // pad rows
        }
    } else {
        int i = (b - nsb - ncb) * 256 + tid;   // 0..16383
        int m = i >> 12, r = i & 4095;
        int n = r >> 6, k = r & 63;
        const float* w = (m == 0) ? w1_0 : (m == 1) ? w2_0 : (m == 2) ? w1_1 : w2_1;
        wt[i] = f2bf(w[k * 64 + n]);
    }
}

// R14 (kept): one block per 64-node slice. Reads the slice's edge log, builds
// per-node buckets in LDS (LDS atomics only), writes deg + buf out fully
// coalesced. Unused bucket slots zeroed (masked reads then hit node 0).
__global__ __launch_bounds__(256) void bucketize_kernel(
    const unsigned* __restrict__ gcur, const unsigned* __restrict__ elog,
    int* __restrict__ deg, unsigned short* __restrict__ buf)
{
    __shared__ int sdeg[64];
    __shared__ unsigned short sbuf[64][CAP];   // 7168 B

    const int g   = blockIdx.x;
    const int tid = threadIdx.x;

    unsigned* zb = (unsigned*)&sbuf[0][0];
    for (int i = tid; i < 64 * CAP / 2; i += 256) zb[i] = 0;
    if (tid < 64) sdeg[tid] = 0;
    int cnt = (int)gcur[g]; if (cnt > LSLOT) cnt = LSLOT;
    __syncthreads();

    for (int i = tid; i < cnt; i += 256) {
        unsigned v = elog[(size_t)g * LSLOT + i];
        int dl = (v >> 16) & 63;
        int p  = atomicAdd(&sdeg[dl], 1);
        if (p < CAP) sbuf[dl][p] = (unsigned short)(v & 0xffffu);
    }
    __syncthreads();

    const unsigned* sb = (const unsigned*)&sbuf[0][0];
    unsigned* gbuf = (unsigned*)(buf + (size_t)g * 64 * CAP);
    for (int i = tid; i < 64 * CAP / 2; i += 256) gbuf[i] = sb[i];
    if (tid < 64) deg[g * 64 + tid] = sdeg[tid];
}

// agg[n] = xb[n] + sum_{s in bucket[n]} xb[s]  (bf16 in, fp32 acc, bf16 out).
// R18: TWO nodes per wave, all loads issued up-front.
// Evidence trail: R15/R16 proved wave-count is the asset; R17 proved bytes
// don't matter but issue-dependence does (making group2 conditional on deg
// REGRESSED by serializing its issue behind the deg load). So: per-wave ILP.
// Both nodes' bucket reads issue back-to-back, then 6 row-group loads + 2
// self loads as one independent batch -> two full latency chains overlapped.
// Groups 0-2 unconditional (R14 form); rare dd>24 tail stays conditional.
__global__ __launch_bounds__(256) void gather_kernel(
    const unsigned short* __restrict__ xb, const int* __restrict__ deg,
    const unsigned short* __restrict__ buf, unsigned short* __restrict__ aggb)
{
    const int tid  = threadIdx.x;
    const int lane = tid & 63;
    const int wave = tid >> 6;
    const int n0   = blockIdx.x * 8 + wave * 2;
    const int n1   = n0 + 1;

    const int slot = lane >> 3;        // 0..7
    const int fc   = (lane & 7) << 3;  // bf16 offset 0,8,...,56 (16B per lane)
    const int li   = lane < CAP ? lane : CAP - 1;

    // bucket + degree loads for both nodes: 4 independent loads, issued together
    int idxA = buf[(size_t)n0 * CAP + li];
    int idxB = buf[(size_t)n1 * CAP + li];
    int ddA = deg[n0]; ddA = ddA < CAP ? ddA : CAP;
    int ddB = deg[n1]; ddB = ddB < CAP ? ddB : CAP;

    // self rows (slot0 lanes only; others stay 0)
    uint4 uA = make_uint4(0u, 0u, 0u, 0u), uB = uA;
    if (slot == 0) {
        uA = *(const uint4*)(xb + (size_t)n0 * D + fc);
        uB = *(const uint4*)(xb + (size_t)n1 * D + fc);
    }

    int sA[3], sB[3];
    #pragma unroll
    for (int g = 0; g < 3; ++g) {
        sA[g] = __shfl(idxA, (g << 3) + slot);
        sB[g] = __shfl(idxB, (g << 3) + slot);
    }

    // 6 independent row loads, back-to-back issue (covers 98% of nodes each)
    uint4 vA0 = *(const uint4*)(xb + (size_t)sA[0] * D + fc);
    uint4 vA1 = *(const uint4*)(xb + (size_t)sA[1] * D + fc);
    uint4 vA2 = *(const uint4*)(xb + (size_t)sA[2] * D + fc);
    uint4 vB0 = *(const uint4*)(xb + (size_t)sB[0] * D + fc);
    uint4 vB1 = *(const uint4*)(xb + (size_t)sB[1] * D + fc);
    uint4 vB2 = *(const uint4*)(xb + (size_t)sB[2] * D + fc);

    float a[8] = {0.f, 0.f, 0.f, 0.f, 0.f, 0.f, 0.f, 0.f};
    float b[8] = {0.f, 0.f, 0.f, 0.f, 0.f, 0.f, 0.f, 0.f};

    if (ddA > 24) {   // wave-uniform, ~2% of nodes
        #pragma unroll
        for (int g = 3; g < 7; ++g) {
            int sg = __shfl(idxA, (g << 3) + slot);
            uint4 v = *(const uint4*)(xb + (size_t)sg * D + fc);
            float m = ((g << 3) + slot) < ddA ? 1.0f : 0.0f;
            a[0] += bf_lo(v.x) * m; a[1] += bf_hi(v.x) * m;
            a[2] += bf_lo(v.y) * m; a[3] += bf_hi(v.y) * m;
            a[4] += bf_lo(v.z) * m; a[5] += bf_hi(v.z) * m;
            a[6] += bf_lo(v.w) * m; a[7] += bf_hi(v.w) * m;
        }
    }
    if (ddB > 24) {   // wave-uniform, ~2% of nodes
        #pragma unroll
        for (int g = 3; g < 7; ++g) {
            int sg = __shfl(idxB, (g << 3) + slot);
            uint4 v = *(const uint4*)(xb + (size_t)sg * D + fc);
            float m = ((g << 3) + slot) < ddB ? 1.0f : 0.0f;
            b[0] += bf_lo(v.x) * m; b[1] += bf_hi(v.x) * m;
            b[2] += bf_lo(v.y) * m; b[3] += bf_hi(v.y) * m;
            b[4] += bf_lo(v.z) * m; b[5] += bf_hi(v.z) * m;
            b[6] += bf_lo(v.w) * m; b[7] += bf_hi(v.w) * m;
        }
    }

    {   // node A: groups 0-2 (masked) + self
        float m0 = (slot      < ddA) ? 1.0f : 0.0f;
        float m1 = (slot +  8 < ddA) ? 1.0f : 0.0f;
        float m2 = (slot + 16 < ddA) ? 1.0f : 0.0f;
        a[0] += bf_lo(vA0.x) * m0 + bf_lo(vA1.x) * m1 + bf_lo(vA2.x) * m2 + bf_lo(uA.x);
        a[1] += bf_hi(vA0.x) * m0 + bf_hi(vA1.x) * m1 + bf_hi(vA2.x) * m2 + bf_hi(uA.x);
        a[2] += bf_lo(vA0.y) * m0 + bf_lo(vA1.y) * m1 + bf_lo(vA2.y) * m2 + bf_lo(uA.y);
        a[3] += bf_hi(vA0.y) * m0 + bf_hi(vA1.y) * m1 + bf_hi(vA2.y) * m2 + bf_hi(uA.y);
        a[4] += bf_lo(vA0.z) * m0 + bf_lo(vA1.z) * m1 + bf_lo(vA2.z) * m2 + bf_lo(uA.z);
        a[5] += bf_hi(vA0.z) * m0 + bf_hi(vA1.z) * m1 + bf_hi(vA2.z) * m2 + bf_hi(uA.z);
        a[6] += bf_lo(vA0.w) * m0 + bf_lo(vA1.w) * m1 + bf_lo(vA2.w) * m2 + bf_lo(uA.w);
        a[7] += bf_hi(vA0.w) * m0 + bf_hi(vA1.w) * m1 + bf_hi(vA2.w) * m2 + bf_hi(uA.w);
    }
    {   // node B: groups 0-2 (masked) + self
        float m0 = (slot      < ddB) ? 1.0f : 0.0f;
        float m1 = (slot +  8 < ddB) ? 1.0f : 0.0f;
        float m2 = (slot + 16 < ddB) ? 1.0f : 0.0f;
        b[0] += bf_lo(vB0.x) * m0 + bf_lo(vB1.x) * m1 + bf_lo(vB2.x) * m2 + bf_lo(uB.x);
        b[1] += bf_hi(vB0.x) * m0 + bf_hi(vB1.x) * m1 + bf_hi(vB2.x) * m2 + bf_hi(uB.x);
        b[2] += bf_lo(vB0.y) * m0 + bf_lo(vB1.y) * m1 + bf_lo(vB2.y) * m2 + bf_lo(uB.y);
        b[3] += bf_hi(vB0.y) * m0 + bf_hi(vB1.y) * m1 + bf_hi(vB2.y) * m2 + bf_hi(uB.y);
        b[4] += bf_lo(vB0.z) * m0 + bf_lo(vB1.z) * m1 + bf_lo(vB2.z) * m2 + bf_lo(uB.z);
        b[5] += bf_hi(vB0.z) * m0 + bf_hi(vB1.z) * m1 + bf_hi(vB2.z) * m2 + bf_hi(uB.z);
        b[6] += bf_lo(vB0.w) * m0 + bf_lo(vB1.w) * m1 + bf_lo(vB2.w) * m2 + bf_lo(uB.w);
        b[7] += bf_hi(vB0.w) * m0 + bf_hi(vB1.w) * m1 + bf_hi(vB2.w) * m2 + bf_hi(uB.w);
    }

    #pragma unroll
    for (int m = 8; m <= 32; m <<= 1) {
        #pragma unroll
        for (int q = 0; q < 8; ++q) { a[q] += __shfl_xor(a[q], m); b[q] += __shfl_xor(b[q], m); }
    }
    if (slot == 0) {
        uint4 o;
        o.x = (unsigned)f2bf(a[0]) | ((unsigned)f2bf(a[1]) << 16);
        o.y = (unsigned)f2bf(a[2]) | ((unsigned)f2bf(a[3]) << 16);
        o.z = (unsigned)f2bf(a[4]) | ((unsigned)f2bf(a[5]) << 16);
        o.w = (unsigned)f2bf(a[6]) | ((unsigned)f2bf(a[7]) << 16);
        *(uint4*)(aggb + (size_t)n0 * D + fc) = o;
        o.x = (unsigned)f2bf(b[0]) | ((unsigned)f2bf(b[1]) << 16);
        o.y = (unsigned)f2bf(b[2]) | ((unsigned)f2bf(b[3]) << 16);
        o.z = (unsigned)f2bf(b[4]) | ((unsigned)f2bf(b[5]) << 16);
        o.w = (unsigned)f2bf(b[6]) | ((unsigned)f2bf(b[7]) << 16);
        *(uint4*)(aggb + (size_t)n1 * D + fc) = o;
    }
}

// out = tanh(h @ W1 + b1) @ W2 + b2 via mfma_f32_16x16x32_bf16.
// Block = 64 nodes x 64 feats, 4 waves; wave w owns node rows 16w..16w+15.
// C/D: col=lane&15, row=quad*4+reg (m89-verified). Wave-private tanh LDS
// round-trip between the matmuls -> no barrier. Rows padded to 72 bf16.
template <bool WRITE_BF16>
__global__ __launch_bounds__(256) void gin_dense_mfma(
    const unsigned short* __restrict__ hb, int n_nodes,
    const unsigned short* __restrict__ w1t, const float* __restrict__ b1,
    const unsigned short* __restrict__ w2t, const float* __restrict__ b2,
    float* __restrict__ out_f, unsigned short* __restrict__ out_b)
{
    __shared__ unsigned short sh [64][72];
    __shared__ unsigned short st [64][72];
    __shared__ unsigned short sw1[64][72];
    __shared__ unsigned short sw2[64][72];

    const int t    = threadIdx.x;
    const int lane = t & 63;
    const int wave = t >> 6;
    const int quad = lane >> 4;
    const int col  = lane & 15;
    const int nb   = blockIdx.x * 64;

    for (int c = t; c < 512; c += 256) {
        int row = c >> 3, c8 = (c & 7) << 3;
        *(uint4*)&sh [row][c8] = *(const uint4*)(hb  + (size_t)(nb + row) * D + c8);
        *(uint4*)&sw1[row][c8] = *(const uint4*)(w1t + row * D + c8);
        *(uint4*)&sw2[row][c8] = *(const uint4*)(w2t + row * D + c8);
    }
    __syncthreads();

    const int arow = 16 * wave + col;
    const int koff = quad << 3;

    short8 a0 = *(const short8*)&sh[arow][koff];
    short8 a1 = *(const short8*)&sh[arow][32 + koff];

    #pragma unroll
    for (int nt = 0; nt < 4; ++nt) {
        int n = (nt << 4) + col;
        short8 bw0 = *(const short8*)&sw1[n][koff];
        short8 bw1 = *(const short8*)&sw1[n][32 + koff];
        float bv = b1[n];
        f32x4 c = {bv, bv, bv, bv};
        c = __builtin_amdgcn_mfma_f32_16x16x32_bf16(a0, bw0, c, 0, 0, 0);
        c = __builtin_amdgcn_mfma_f32_16x16x32_bf16(a1, bw1, c, 0, 0, 0);
        #pragma unroll
        for (int r = 0; r < 4; ++r)
            st[16 * wave + (quad << 2) + r][n] = f2bf(tanhf(c[r]));
    }
    // no __syncthreads: each wave reads back exactly the rows it wrote

    short8 p0 = *(const short8*)&st[arow][koff];
    short8 p1 = *(const short8*)&st[arow][32 + koff];

    #pragma unroll
    for (int nt = 0; nt < 4; ++nt) {
        int n = (nt << 4) + col;
        short8 bw0 = *(const short8*)&sw2[n][koff];
        short8 bw1 = *(const short8*)&sw2[n][32 + koff];
        float bv = b2[n];
        f32x4 c = {bv, bv, bv, bv};
        c = __builtin_amdgcn_mfma_f32_16x16x32_bf16(p0, bw0, c, 0, 0, 0);
        c = __builtin_amdgcn_mfma_f32_16x16x32_bf16(p1, bw1, c, 0, 0, 0);
        #pragma unroll
        for (int r = 0; r < 4; ++r) {
            int row = nb + 16 * wave + (quad << 2) + r;
            if (WRITE_BF16) {
                out_b[(size_t)row * D + n] = f2bf(c[r]);   // x1b sized n_pad: no clamp
            } else if (row < n_nodes) {
                out_f[(size_t)row * D + n] = c[r];
            }
        }
    }
}

extern "C" void kernel_launch(void* const* d_in, const int* in_sizes, int n_in,
                              void* d_out, int out_size, void* d_ws, size_t ws_size,
                              hipStream_t stream)
{
    const float* x    = (const float*)d_in[0];
    const int*   src  = (const int*)  d_in[1];
    const int*   dst  = (const int*)  d_in[2];
    const float* w1_0 = (const float*)d_in[3];
    const float* b1_0 = (const float*)d_in[4];
    const float* w2_0 = (const float*)d_in[5];
    const float* b2_0 = (const float*)d_in[6];
    const float* w1_1 = (const float*)d_in[7];
    const float* b1_1 = (const float*)d_in[8];
    const float* w2_1 = (const float*)d_in[9];
    const float* b2_1 = (const float*)d_in[10];
    float* out = (float*)d_out;

    const int n_nodes = in_sizes[0] / D;        // 50000
    const int n_edges = in_sizes[1];            // 800000
    const int n_pad   = (n_nodes + 63) & ~63;   // 50048
    const int S       = n_pad >> 6;             // 782 slices of 64 nodes

    // ws: gcur (u32[S]) | elog | deg | buf | aggb | xb | x1b | wt
    unsigned*       gcur = (unsigned*)d_ws;
    unsigned*       elog = gcur + S;
    int*            deg  = (int*)(elog + (size_t)S * LSLOT);
    unsigned short* buf  = (unsigned short*)(deg + n_pad);
    unsigned short* aggb = buf  + (size_t)n_pad * CAP;
    unsigned short* xb   = aggb + (size_t)n_pad * D;
    unsigned short* x1b  = xb   + (size_t)n_pad * D;
    unsigned short* wt   = x1b  + (size_t)n_pad * D;

    const int n4  = n_nodes * D / 4;             // 800000
    const int n4p = n_pad * D / 4;               // 800768 (pad rows zeroed)
    const int ncb = (n4p + 255) / 256;
    const int nsb = (n_edges + ACH - 1) / ACH;   // 128 slice-scatter blocks

    hipMemsetAsync(gcur, 0, (size_t)S * sizeof(unsigned), stream);
    prep_scatter_kernel<<<nsb + ncb + 64, 256, 0, stream>>>(
        src, dst, gcur, elog, n_edges, S, nsb,
        x, xb, n4, n4p, ncb,
        w1_0, w2_0, w1_1, w2_1, wt);
    bucketize_kernel<<<S, 256, 0, stream>>>(gcur, elog, deg, buf);

    const int gather_blocks = n_pad / 8;      // 6256 (2 nodes/wave)
    const int dense_blocks  = n_pad / 64;     // 782

    // layer 0
    gather_kernel<<<gather_blocks, 256, 0, stream>>>(xb, deg, buf, aggb);
    gin_dense_mfma<true><<<dense_blocks, 256, 0, stream>>>(
        aggb, n_nodes, wt, b1_0, wt + 4096, b2_0, nullptr, x1b);
    // layer 1
    gather_kernel<<<gather_blocks, 256, 0, stream>>>(x1b, deg, buf, aggb);
    gin_dense_mfma<false><<<dense_blocks, 256, 0, stream>>>(
        aggb, n_nodes, wt + 8192, b1_1, wt + 12288, b2_1, out, nullptr);
}